// Round 3
// baseline (544.538 us; speedup 1.0000x reference)
//
#include <hip/hip_runtime.h>
#include <hip/hip_fp16.h>

typedef __attribute__((ext_vector_type(4))) float     f32x4;
typedef __attribute__((ext_vector_type(8))) _Float16  f16x8;
typedef __attribute__((ext_vector_type(4))) _Float16  f16x4;

#define MFMA(a, b, c) __builtin_amdgcn_mfma_f32_16x16x32_f16(a, b, c, 0, 0, 0)

static constexpr float SCALE = 0.17677669529663687f;   // 32^-0.5
static constexpr float LOG2E = 1.4426950408889634f;

// ---- LDS layout (bytes), total 128 KiB, 1 block/CU ----
// OFF_X   : x tile [64 tok][192 ch] f16 (row 384B, swizzled) — reused as attn-out
// OFF_QKV : per head 12288B = q[64][32] + k[64][32] + vT[32][64] (all f16, swizzled)
// OFF_P   : per wave 2048B = P~[16][64] f16 (row 128B, swizzled)
// OFF_BIAS: rel-pos bias [64][64] f32
static constexpr unsigned OFF_X    = 0;
static constexpr unsigned OFF_QKV  = 24576;
static constexpr unsigned OFF_P    = 24576 + 73728;          // 98304
static constexpr unsigned OFF_BIAS = 98304 + 16384;          // 114688
static constexpr unsigned LDS_BYTES = 131072;

__device__ __forceinline__ unsigned swz(unsigned byte, int row) {
    // XOR a row-derived value into the 16B-slot bits: breaks the 8/16/32-way
    // bank conflicts of power-of-two row strides (guide §6 G4 / T2).
    return byte ^ ((unsigned)(row & 7) << 4);
}

// Prologue: weights -> fp16 in FRAGMENT-READY layout + 64x64 rel-pos bias gather.
// Layout (elements): idx = nt*3072 + ks*512 + lane*8 + e   (lane = lgrp*16+lrow)
// holding W[n=nt*16+lrow][k=ks*32+lgrp*8+e] — one wave's B-fragment for a
// given (nt,ks) is 1024 CONTIGUOUS bytes (coalesced dwordx4 per lane).
// Re-run every call (d_ws is re-poisoned before each timed launch).
__global__ __launch_bounds__(256)
void wa_prep(const float* __restrict__ wq, const float* __restrict__ wo,
             const float* __restrict__ pos,
             _Float16* __restrict__ wq16, _Float16* __restrict__ wo16,
             float* __restrict__ biasw) {
    const int i = blockIdx.x * 256 + threadIdx.x;   // grid covers 110592
    if (i < 110592) {                                // qkv weight: 36 n-tiles
        const int e    = i & 7;
        const int lrow = (i >> 3) & 15;
        const int lgrp = (i >> 7) & 3;
        const int ksnt = i >> 9;                     // nt*6 + ks
        const int ks   = ksnt % 6;
        const int nt   = ksnt / 6;
        const int n = nt * 16 + lrow;
        const int k = ks * 32 + lgrp * 8 + e;
        wq16[i] = (_Float16)wq[n * 192 + k];
    }
    if (i < 36864) {                                 // out weight: 12 n-tiles
        const int e    = i & 7;
        const int lrow = (i >> 3) & 15;
        const int lgrp = (i >> 7) & 3;
        const int ksnt = i >> 9;
        const int ks   = ksnt % 6;
        const int nt   = ksnt / 6;
        const int n = nt * 16 + lrow;
        const int k = ks * 32 + lgrp * 8 + e;
        wo16[i] = (_Float16)wo[n * 192 + k];
    }
    if (i < 4096) {
        const int qi = i >> 6, kj = i & 63;
        const int yi = qi >> 3, xi = qi & 7;
        const int yj = kj >> 3, xj = kj & 7;
        biasw[i] = pos[(yi - yj + 7) * 15 + (xi - xj + 7)];
    }
}

// One block = one 8x8 window (64 tokens), 512 threads = 8 waves.
// Fully fused: roll + QKV proj + 6-head attention + out proj + inverse roll.
__global__ __launch_bounds__(512, 1)
void wa_fused(const float* __restrict__ x,
              const _Float16* __restrict__ wq16,
              const _Float16* __restrict__ wo16,
              const float* __restrict__ b_out,
              const float* __restrict__ biasg,
              float* __restrict__ out) {
    extern __shared__ char smem[];
    const int tid  = threadIdx.x;
    const int lane = tid & 63;
    const int wid  = tid >> 6;        // wave 0..7
    const int lrow = lane & 15;       // MFMA row/col within 16x16 tile
    const int lgrp = lane >> 4;       // MFMA k-group / C-row group

    const int blk = blockIdx.x;       // 4096 = b(4) * wy(32) * wx(32)
    const int b   = blk >> 10;
    const int wy  = (blk >> 5) & 31;
    const int wx  = blk & 31;

    // ================= phase 1: x tile (rolled) -> LDS f16, bias -> LDS ====
    for (int i = tid; i < 64 * 48; i += 512) {
        const int tok = i / 48;
        const int f4  = i - tok * 48;                 // float4 index in row
        const int ty = tok >> 3, tx = tok & 7;
        const int hh = ((wy << 3) + ty + 4) & 255;    // roll(-4) source coord
        const int ww = ((wx << 3) + tx + 4) & 255;
        const float4 v = *reinterpret_cast<const float4*>(
            x + ((((size_t)b << 8) + hh) * 256 + ww) * 192 + f4 * 4);
        f16x4 h;
        h[0] = (_Float16)v.x; h[1] = (_Float16)v.y;
        h[2] = (_Float16)v.z; h[3] = (_Float16)v.w;
        *reinterpret_cast<f16x4*>(smem + swz(OFF_X + tok * 384 + f4 * 8, tok)) = h;
    }
    {
        float* bl = reinterpret_cast<float*>(smem + OFF_BIAS);
        for (int i = tid; i < 4096; i += 512) bl[i] = biasg[i];
    }
    __syncthreads();

    // ================= phase 2: QKV GEMM  (M=64, N=576, K=192) =============
    // wave grid 2(M) x 4(N): waves share A across N-partners.
    {
        const int wm = wid >> 2;      // 0..1 -> M-tiles {2wm, 2wm+1}
        const int wn = wid & 3;       // 0..3 -> N-tiles wn*9 .. wn*9+8
        f16x8 afr[2][6];
        #pragma unroll
        for (int mt = 0; mt < 2; ++mt) {
            const int row = ((wm * 2 + mt) << 4) + lrow;
            #pragma unroll
            for (int ks = 0; ks < 6; ++ks)
                afr[mt][ks] = *reinterpret_cast<const f16x8*>(
                    smem + swz(OFF_X + row * 384 + ks * 64 + lgrp * 16, row));
        }
        for (int nt0 = 0; nt0 < 9; ++nt0) {
            const int nt = wn * 9 + nt0;
            // fragment-ready weights: idx = nt*3072 + ks*512 + lane*8
            const _Float16* wbase = wq16 + (size_t)nt * 3072 + lane * 8;
            f32x4 acc0 = {0.f, 0.f, 0.f, 0.f}, acc1 = {0.f, 0.f, 0.f, 0.f};
            #pragma unroll
            for (int ks = 0; ks < 6; ++ks) {
                const f16x8 bfr = *reinterpret_cast<const f16x8*>(wbase + ks * 512);
                acc0 = MFMA(afr[0][ks], bfr, acc0);
                acc1 = MFMA(afr[1][ks], bfr, acc1);
            }
            // n -> (qkv, head, d):  n = qkv*192 + head*32 + d
            const int buf   = nt / 12;          // 0=q, 1=k, 2=v  (wave-uniform)
            const int head  = (nt % 12) >> 1;
            const int d     = ((nt & 1) << 4) + lrow;
            const unsigned hb = OFF_QKV + head * 12288;
            if (buf < 2) {                       // q,k stored [tok][d]
                const unsigned base = hb + buf * 4096;
                #pragma unroll
                for (int mt = 0; mt < 2; ++mt) {
                    const f32x4 a = mt ? acc1 : acc0;
                    #pragma unroll
                    for (int r = 0; r < 4; ++r) {
                        const int tok = ((wm * 2 + mt) << 4) + (lgrp << 2) + r;
                        *reinterpret_cast<_Float16*>(
                            smem + swz(base + tok * 64 + d * 2, tok)) = (_Float16)a[r];
                    }
                }
            } else {                             // v stored transposed [d][tok]
                const unsigned base = hb + 8192;
                #pragma unroll
                for (int mt = 0; mt < 2; ++mt) {
                    const f32x4 a = mt ? acc1 : acc0;
                    const int tok0 = ((wm * 2 + mt) << 4) + (lgrp << 2);
                    f16x4 h;
                    #pragma unroll
                    for (int r = 0; r < 4; ++r) h[r] = (_Float16)a[r];
                    *reinterpret_cast<f16x4*>(
                        smem + swz(base + d * 128 + tok0 * 2, d)) = h;
                }
            }
        }
    }
    __syncthreads();

    // ================= phase 3: attention, 24 units (head x mtile), 3/wave ==
    {
        const float* bl = reinterpret_cast<const float*>(smem + OFF_BIAS);
        const unsigned pbase = OFF_P + wid * 2048;
        for (int u = 0; u < 3; ++u) {
            const int unit  = wid + (u << 3);    // 0..23
            const int head  = unit >> 2;
            const int mtile = unit & 3;
            const unsigned hb = OFF_QKV + head * 12288;

            // ---- QK^T for rows mtile*16..+15, all 64 cols (K = d = 32) ----
            const int qrow = (mtile << 4) + lrow;
            const f16x8 qa = *reinterpret_cast<const f16x8*>(
                smem + swz(hb + qrow * 64 + lgrp * 16, qrow));
            f32x4 acc[4];
            #pragma unroll
            for (int nt = 0; nt < 4; ++nt) {
                const int krow = (nt << 4) + lrow;
                const f16x8 kb = *reinterpret_cast<const f16x8*>(
                    smem + swz(hb + 4096 + krow * 64 + lgrp * 16, krow));
                const f32x4 z = {0.f, 0.f, 0.f, 0.f};
                acc[nt] = MFMA(qa, kb, z);
            }

            // ---- scale + bias, softmax (rows live on 16 consecutive lanes) -
            float vals[4][4], mx[4], sm[4];
            #pragma unroll
            for (int r = 0; r < 4; ++r) mx[r] = -1e30f;
            #pragma unroll
            for (int nt = 0; nt < 4; ++nt)
                #pragma unroll
                for (int r = 0; r < 4; ++r) {
                    const float v = acc[nt][r] * SCALE +
                        bl[((mtile << 4) + (lgrp << 2) + r) * 64 + (nt << 4) + lrow];
                    vals[nt][r] = v;
                    mx[r] = fmaxf(mx[r], v);
                }
            #pragma unroll
            for (int m = 1; m < 16; m <<= 1)
                #pragma unroll
                for (int r = 0; r < 4; ++r)
                    mx[r] = fmaxf(mx[r], __shfl_xor(mx[r], m, 64));
            #pragma unroll
            for (int r = 0; r < 4; ++r) sm[r] = 0.f;
            #pragma unroll
            for (int nt = 0; nt < 4; ++nt)
                #pragma unroll
                for (int r = 0; r < 4; ++r) {
                    const float e = exp2f((vals[nt][r] - mx[r]) * LOG2E);
                    vals[nt][r] = e;
                    sm[r] += e;
                }
            #pragma unroll
            for (int m = 1; m < 16; m <<= 1)
                #pragma unroll
                for (int r = 0; r < 4; ++r)
                    sm[r] += __shfl_xor(sm[r], m, 64);

            // ---- P~ to LDS (unnormalized; divide folded into PV epilogue) --
            #pragma unroll
            for (int nt = 0; nt < 4; ++nt)
                #pragma unroll
                for (int r = 0; r < 4; ++r) {
                    const int row = (lgrp << 2) + r;
                    *reinterpret_cast<_Float16*>(
                        smem + swz(pbase + row * 128 + ((nt << 4) + lrow) * 2, row)) =
                        (_Float16)vals[nt][r];
                }
            float rinv[4];
            #pragma unroll
            for (int r = 0; r < 4; ++r) rinv[r] = 1.f / sm[r];

            // ---- PV: out[16][32] = P~[16][64] @ v[64][32]  (2 ksteps) ------
            f32x4 o0 = {0.f, 0.f, 0.f, 0.f}, o1 = {0.f, 0.f, 0.f, 0.f};
            #pragma unroll
            for (int ks = 0; ks < 2; ++ks) {
                const f16x8 pa = *reinterpret_cast<const f16x8*>(
                    smem + swz(pbase + lrow * 128 + ks * 64 + lgrp * 16, lrow));
                const f16x8 vb0 = *reinterpret_cast<const f16x8*>(
                    smem + swz(hb + 8192 + lrow * 128 + ks * 64 + lgrp * 16, lrow));
                const f16x8 vb1 = *reinterpret_cast<const f16x8*>(
                    smem + swz(hb + 8192 + (16 + lrow) * 128 + ks * 64 + lgrp * 16, 16 + lrow));
                o0 = MFMA(pa, vb0, o0);
                o1 = MFMA(pa, vb1, o1);
            }
            // ---- normalize + store attn-out into OFF_X region (f16) --------
            #pragma unroll
            for (int r = 0; r < 4; ++r) {
                const int tok = (mtile << 4) + (lgrp << 2) + r;
                const int ch0 = head * 32 + lrow;
                *reinterpret_cast<_Float16*>(
                    smem + swz(OFF_X + tok * 384 + ch0 * 2, tok)) =
                    (_Float16)(o0[r] * rinv[r]);
                *reinterpret_cast<_Float16*>(
                    smem + swz(OFF_X + tok * 384 + (ch0 + 16) * 2, tok)) =
                    (_Float16)(o1[r] * rinv[r]);
            }
        }
    }
    __syncthreads();

    // ================= phase 4: out proj (M=64, N=192, K=192) + bias + roll =
    {
        const int wm = wid >> 2;
        const int wn = wid & 3;       // N-tiles wn*3 .. wn*3+2
        f16x8 afr[2][6];
        #pragma unroll
        for (int mt = 0; mt < 2; ++mt) {
            const int row = ((wm * 2 + mt) << 4) + lrow;
            #pragma unroll
            for (int ks = 0; ks < 6; ++ks)
                afr[mt][ks] = *reinterpret_cast<const f16x8*>(
                    smem + swz(OFF_X + row * 384 + ks * 64 + lgrp * 16, row));
        }
        #pragma unroll
        for (int nt0 = 0; nt0 < 3; ++nt0) {
            const int nt = wn * 3 + nt0;
            const int o  = (nt << 4) + lrow;
            // fragment-ready weights: idx = nt*3072 + ks*512 + lane*8
            const _Float16* wbase = wo16 + (size_t)nt * 3072 + lane * 8;
            f32x4 acc0 = {0.f, 0.f, 0.f, 0.f}, acc1 = {0.f, 0.f, 0.f, 0.f};
            #pragma unroll
            for (int ks = 0; ks < 6; ++ks) {
                const f16x8 bfr = *reinterpret_cast<const f16x8*>(wbase + ks * 512);
                acc0 = MFMA(afr[0][ks], bfr, acc0);
                acc1 = MFMA(afr[1][ks], bfr, acc1);
            }
            const float bo = b_out[o];
            #pragma unroll
            for (int mt = 0; mt < 2; ++mt) {
                const f32x4 a = mt ? acc1 : acc0;
                #pragma unroll
                for (int r = 0; r < 4; ++r) {
                    const int tok = ((wm * 2 + mt) << 4) + (lgrp << 2) + r;
                    const int ty = tok >> 3, tx = tok & 7;
                    const int hh = ((wy << 3) + ty + 4) & 255;   // roll(+4) dest
                    const int ww = ((wx << 3) + tx + 4) & 255;
                    out[((((size_t)b << 8) + hh) * 256 + ww) * 192 + o] = a[r] + bo;
                }
            }
        }
    }
}

extern "C" void kernel_launch(void* const* d_in, const int* in_sizes, int n_in,
                              void* d_out, int out_size, void* d_ws, size_t ws_size,
                              hipStream_t stream) {
    const float* x   = (const float*)d_in[0];
    const float* wq  = (const float*)d_in[1];
    const float* pos = (const float*)d_in[2];
    const float* wo  = (const float*)d_in[3];
    const float* bo  = (const float*)d_in[4];
    float* out = (float*)d_out;

    _Float16* wq16 = (_Float16*)d_ws;                               // 221184 B
    _Float16* wo16 = (_Float16*)((char*)d_ws + 221184);             //  73728 B
    float*    bias = (float*)((char*)d_ws + 221184 + 73728);        //  16384 B

    (void)hipFuncSetAttribute((const void*)wa_fused,
                              hipFuncAttributeMaxDynamicSharedMemorySize,
                              (int)LDS_BYTES);

    wa_prep<<<dim3(432), dim3(256), 0, stream>>>(wq, wo, pos, wq16, wo16, bias);
    wa_fused<<<dim3(4096), dim3(512), LDS_BYTES, stream>>>(x, wq16, wo16, bo, bias, out);
}